// Round 18
// baseline (194.886 us; speedup 1.0000x reference)
//
#include <hip/hip_runtime.h>
#include <hip/hip_bf16.h>

typedef __bf16 bf16_t;
typedef bf16_t bf16x8 __attribute__((ext_vector_type(8)));
typedef float  f32x4  __attribute__((ext_vector_type(4)));
typedef unsigned long long u64;
typedef unsigned int u32;

#define MFMA16(A,B,C) __builtin_amdgcn_mfma_f32_16x16x32_bf16((A),(B),(C),0,0,0)

// NQ=16384, NK=4096, QDIM=512, KDIM=256, MID=256

// async global -> LDS, 16B per lane; LDS dest = wave-uniform base + lane*16.
static __device__ __forceinline__ void gl_lds16(const bf16_t* g, void* l) {
    __builtin_amdgcn_global_load_lds(
        (const __attribute__((address_space(1))) u32*)(const void*)g,
        (__attribute__((address_space(3))) u32*)l, 16, 0, 0);
}

// ---------------------------------------------------------------------------
// C_bf16[M][256] = (A_f32[M][KA] @ W_f32[256][KA]^T + b[256]) * scale
// SWZ: 16B chunk c of row stored at c ^ (row&7)  (verified r9/r12/r13)
// ---------------------------------------------------------------------------
template<int KA, bool SWZ>
__global__ __launch_bounds__(256)
void proj_kernel(const float* __restrict__ A, const float* __restrict__ W,
                 const float* __restrict__ b, bf16_t* __restrict__ C,
                 float scale)
{
    __shared__ bf16_t Alds[64][40];
    __shared__ bf16_t Wlds[256][40];

    const int t  = threadIdx.x;
    const int w  = t >> 6, l = t & 63, lr = l & 15, lg = l >> 4;
    const int m0 = blockIdx.x * 64;

    f32x4 acc[16];
#pragma unroll
    for (int tt = 0; tt < 16; ++tt) acc[tt] = (f32x4){0.f, 0.f, 0.f, 0.f};

    const int ar  = t >> 2;
    const int ac8 = (t & 3) * 8;

    for (int kb = 0; kb < KA / 32; ++kb) {
        {
            const float* ap = A + (size_t)(m0 + ar) * KA + kb * 32 + ac8;
            float4 a0 = *(const float4*)ap;
            float4 a1 = *(const float4*)(ap + 4);
            bf16x8 av;
            av[0]=(bf16_t)a0.x; av[1]=(bf16_t)a0.y; av[2]=(bf16_t)a0.z; av[3]=(bf16_t)a0.w;
            av[4]=(bf16_t)a1.x; av[5]=(bf16_t)a1.y; av[6]=(bf16_t)a1.z; av[7]=(bf16_t)a1.w;
            *(bf16x8*)&Alds[ar][ac8] = av;
        }
#pragma unroll
        for (int c = 0; c < 4; ++c) {
            int e8 = c * 256 + t;
            int wr = e8 >> 2, wc8 = (e8 & 3) * 8;
            const float* wp = W + (size_t)wr * KA + kb * 32 + wc8;
            float4 w0 = *(const float4*)wp;
            float4 w1 = *(const float4*)(wp + 4);
            bf16x8 wv;
            wv[0]=(bf16_t)w0.x; wv[1]=(bf16_t)w0.y; wv[2]=(bf16_t)w0.z; wv[3]=(bf16_t)w0.w;
            wv[4]=(bf16_t)w1.x; wv[5]=(bf16_t)w1.y; wv[6]=(bf16_t)w1.z; wv[7]=(bf16_t)w1.w;
            *(bf16x8*)&Wlds[wr][wc8] = wv;
        }
        __syncthreads();

        bf16x8 af = *(bf16x8*)&Alds[w * 16 + lr][lg * 8];
#pragma unroll
        for (int tt = 0; tt < 16; ++tt) {
            bf16x8 bfrag = *(bf16x8*)&Wlds[tt * 16 + lr][lg * 8];
            acc[tt] = MFMA16(af, bfrag, acc[tt]);
        }
        __syncthreads();
    }

#pragma unroll
    for (int tt = 0; tt < 16; ++tt) {
        int col = tt * 16 + lr;
        float bias = b[col];
#pragma unroll
        for (int r = 0; r < 4; ++r) {
            int row = m0 + w * 16 + lg * 4 + r;
            int colS = col;
            if (SWZ) colS = (((col >> 3) ^ (row & 7)) << 3) | (col & 7);
            C[(size_t)row * 256 + colS] = (bf16_t)((acc[tt][r] + bias) * scale);
        }
    }
}

// ---------------------------------------------------------------------------
// VT[256][4096] bf16, pre-swizzled within 64-col groups (verified r9/r12):
// VT[d][g*64 + c*8 + j] holds w*S for k = g*64 + (c^(d&7))*8 + j
// ---------------------------------------------------------------------------
__global__ __launch_bounds__(256)
void buildvt_kernel(const float* __restrict__ S, const float* __restrict__ wgt,
                    bf16_t* __restrict__ VT)
{
    int i = blockIdx.x * 256 + threadIdx.x;
    int d = i >> 12, k = i & 4095;
    int kt = (k & ~63) | (((((k >> 3) & 7) ^ (d & 7)) << 3)) | (k & 7);
    VT[i] = (bf16_t)(wgt[kt] * S[(size_t)kt * 256 + d]);
}

// ---------------------------------------------------------------------------
// Flash attention, swapped-QK^T + merged-phase pipeline (r17) + wave skew:
//   iteration t: {mask(t+1); stage V(t+1), K(t+2); even waves QK(t+1)||PV(t),
//   odd waves PV(t)||QK(t+1) (wave-uniform skew de-synchronizes the LDS-heavy
//   and VALU phases across the 8 waves); softmax(t+1); ONE barrier}.
//   512 thr = 8 waves x 16 q; grid (128, SPLIT?2:1); LDS 128 KB.
// ---------------------------------------------------------------------------
template<bool SPLIT>
__global__ __launch_bounds__(512, 2)
void attn_kernel(const bf16_t* __restrict__ Qb, const bf16_t* __restrict__ Kb,
                 const bf16_t* __restrict__ VT, const int* __restrict__ mask,
                 float* __restrict__ out, float* __restrict__ pacc,
                 float* __restrict__ pm, float* __restrict__ pl)
{
    __shared__ __align__(16) char Kraw[2][32768];  // K [64][512B] (pre-swz)
    __shared__ __align__(16) char Vraw[2][32768];  // VT [256][128B] (pre-swz)

    const int t  = threadIdx.x;
    const int w  = t >> 6, l = t & 63, lr = l & 15, lg = l >> 4;
    const int qw = blockIdx.x * 128 + w * 16;      // wave's 16 q-rows
    const int half = SPLIT ? (int)blockIdx.y : 0;
    const int NT   = SPLIT ? 32 : 64;
    const int kb0  = half * NT;

    // hoist Q fragments (lane: q-row = qw+lr, k = kk*32 + lg*8 + j)
    bf16x8 qf[8];
    {
        const bf16_t* qrow = Qb + (size_t)(qw + lr) * 256;
#pragma unroll
        for (int kk = 0; kk < 8; ++kk)
            qf[kk] = *(const bf16x8*)(qrow + kk * 32 + lg * 8);
    }

    bf16x8 vone;
#pragma unroll
    for (int j = 0; j < 8; ++j) vone[j] = (bf16_t)1.0f;

    f32x4 acc[16];                 // C-layout: q = lg*4+r, d = dt*16+lr
#pragma unroll
    for (int dt = 0; dt < 16; ++dt) acc[dt] = (f32x4){0.f, 0.f, 0.f, 0.f};
    f32x4 lacc = (f32x4){0.f, 0.f, 0.f, 0.f};   // row-sum (P @ 1), C-layout
    float mrow = -1e30f;           // running max, per-lane (q = qw+lr)
    bf16x8 pa[2];                  // current tile's P A-frags

    char* const K0 = &Kraw[0][0];
    char* const K1 = &Kraw[1][0];
    char* const V0 = &Vraw[0][0];
    char* const V1 = &Vraw[1][0];

    auto stageK = [&](int kb, char* kd) {
#pragma unroll
        for (int i = 0; i < 4; ++i) {          // K: wave w -> rows w*8..+7
            int row = w * 8 + i * 2 + (l >> 5);
            gl_lds16(Kb + (size_t)(kb * 64 + row) * 256 + (l & 31) * 8,
                     kd + (w * 8 + i * 2) * 512);
        }
    };
    auto stageV = [&](int kb, char* vd) {
#pragma unroll
        for (int i = 0; i < 4; ++i) {          // VT: wave w -> d = w*32..+31
            int d = w * 32 + i * 8 + (l >> 3);
            gl_lds16(VT + (size_t)d * 4096 + kb * 64 + (l & 7) * 8,
                     vd + (w * 32 + i * 8) * 128);
        }
    };

    // S^T = K Q^T: lane (lr,lg) reg (tt,r) = S[kv=16tt+4lg+r][q=qw+lr]
    auto qk = [&](char* kcur, f32x4 (&s)[4]) {
#pragma unroll
        for (int tt = 0; tt < 4; ++tt) {
            f32x4 sv = (f32x4){0.f, 0.f, 0.f, 0.f};
#pragma unroll
            for (int kk = 0; kk < 8; ++kk) {
                bf16x8 kf = *(bf16x8*)(kcur + (((tt * 16 + lr) * 512)
                                | ((((kk * 4 + lg) ^ (lr & 7)) << 4))));
                sv = MFMA16(kf, qf[kk], sv);
            }
            s[tt] = sv;
        }
    };

    // PV(t): acc/lacc += pa . V  (C-layout)
    auto pv = [&](char* vcur) {
        lacc = MFMA16(pa[0], vone, lacc);
        lacc = MFMA16(pa[1], vone, lacc);
#pragma unroll
        for (int dt = 0; dt < 16; ++dt) {
            int vrow = dt * 16 + lr;                   // row&7 = lr&7
            bf16x8 v0 = *(bf16x8*)(vcur + ((vrow * 128)
                            | ((((0 * 4 + lg) ^ (lr & 7)) << 4))));
            bf16x8 v1 = *(bf16x8*)(vcur + ((vrow * 128)
                            | ((((1 * 4 + lg) ^ (lr & 7)) << 4))));
            acc[dt] = MFMA16(pa[0], v0, acc[dt]);
            acc[dt] = MFMA16(pa[1], v1, acc[dt]);
        }
    };

    // mask, row-max, defer-rescale, exp, pack -> pa   (r16-verified)
    auto softmax = [&](int4 (&mv)[4], f32x4 (&s)[4]) {
#pragma unroll
        for (int tt = 0; tt < 4; ++tt) {
            s[tt][0] = mv[tt].x ? s[tt][0] : -1e30f;
            s[tt][1] = mv[tt].y ? s[tt][1] : -1e30f;
            s[tt][2] = mv[tt].z ? s[tt][2] : -1e30f;
            s[tt][3] = mv[tt].w ? s[tt][3] : -1e30f;
        }
        float bm;
        {
            f32x4 m4 = s[0];
#pragma unroll
            for (int tt = 1; tt < 4; ++tt) {
                m4[0] = fmaxf(m4[0], s[tt][0]);
                m4[1] = fmaxf(m4[1], s[tt][1]);
                m4[2] = fmaxf(m4[2], s[tt][2]);
                m4[3] = fmaxf(m4[3], s[tt][3]);
            }
            bm = fmaxf(fmaxf(m4[0], m4[1]), fmaxf(m4[2], m4[3]));
            bm = fmaxf(bm, __shfl_xor(bm, 16));
            bm = fmaxf(bm, __shfl_xor(bm, 32));
        }
        bool need = bm > mrow + 8.f;
        if (__any(need)) {
            float mn = fmaxf(mrow, bm);
            float fr = __expf(mrow - mn);
            mrow = mn;
            float frC[4];
#pragma unroll
            for (int r = 0; r < 4; ++r) frC[r] = __shfl(fr, lg * 4 + r);
#pragma unroll
            for (int r = 0; r < 4; ++r) {
                lacc[r] *= frC[r];
#pragma unroll
                for (int dt = 0; dt < 16; ++dt) acc[dt][r] *= frC[r];
            }
        }
#pragma unroll
        for (int tt = 0; tt < 4; ++tt)
#pragma unroll
            for (int r = 0; r < 4; ++r)
                s[tt][r] = __expf(s[tt][r] - mrow);

#pragma unroll
        for (int g = 0; g < 2; ++g) {
            u32 x0, x1, y0, y1;
            asm("v_cvt_pk_bf16_f32 %0, %1, %2"
                : "=v"(x0) : "v"(s[2 * g][0]), "v"(s[2 * g][1]));
            asm("v_cvt_pk_bf16_f32 %0, %1, %2"
                : "=v"(x1) : "v"(s[2 * g][2]), "v"(s[2 * g][3]));
            asm("v_cvt_pk_bf16_f32 %0, %1, %2"
                : "=v"(y0) : "v"(s[2 * g + 1][0]), "v"(s[2 * g + 1][1]));
            asm("v_cvt_pk_bf16_f32 %0, %1, %2"
                : "=v"(y1) : "v"(s[2 * g + 1][2]), "v"(s[2 * g + 1][3]));
            asm volatile("v_permlane32_swap_b32 %0, %1" : "+v"(x0), "+v"(y0));
            asm volatile("v_permlane32_swap_b32 %0, %1" : "+v"(x1), "+v"(y1));
            u32 sx0 = (u32)__shfl_xor((int)x0, 16);
            u32 sx1 = (u32)__shfl_xor((int)x1, 16);
            u32 sy0 = (u32)__shfl_xor((int)y0, 16);
            u32 sy1 = (u32)__shfl_xor((int)y1, 16);
            bool evn = (lg & 1) == 0;
            union { u32 uw[4]; bf16x8 v; } pu;
            pu.uw[0] = evn ? x0  : sy0;
            pu.uw[1] = evn ? x1  : sy1;
            pu.uw[2] = evn ? sx0 : y0;
            pu.uw[3] = evn ? sx1 : y1;
            pa[g] = pu.v;
        }
    };

    // ---- prologue: tile 0 staged, QK(0)+softmax(0) -> pa; K(1) staged
    stageV(kb0, V0);
    stageK(kb0, K0);
    __syncthreads();
    {
        int4 mv[4];
#pragma unroll
        for (int tt = 0; tt < 4; ++tt)
            mv[tt] = *(const int4*)(mask + (size_t)(qw + lr) * 4096
                                    + kb0 * 64 + tt * 16 + lg * 4);
        f32x4 s[4];
        qk(K0, s);
        softmax(mv, s);
    }
    stageK(kb0 + 1, K1);
    __syncthreads();

    // ---- main pipeline: iter tb computes QK(tb+1) || PV(tb), wave-skewed
    for (int tb = 0; tb < NT - 1; ++tb) {
        char* kQ = (tb & 1) ? K0 : K1;   // QK(tb+1) source
        char* vP = (tb & 1) ? V1 : V0;   // PV(tb) source
        char* kS = (tb & 1) ? K1 : K0;   // stage K(tb+2) dest
        char* vS = (tb & 1) ? V0 : V1;   // stage V(tb+1) dest
        const int kb = kb0 + tb;

        int4 mv[4];
#pragma unroll
        for (int tt = 0; tt < 4; ++tt)
            mv[tt] = *(const int4*)(mask + (size_t)(qw + lr) * 4096
                                    + (kb + 1) * 64 + tt * 16 + lg * 4);

        stageV(kb + 1, vS);
        if (tb + 2 < NT) stageK(kb + 2, kS);

        __builtin_amdgcn_s_setprio(1);
        f32x4 s[4];
        if (w & 1) {       // wave-uniform skew: odd waves PV first
            pv(vP);
            qk(kQ, s);
        } else {
            qk(kQ, s);
            pv(vP);
        }
        __builtin_amdgcn_s_setprio(0);

        softmax(mv, s);   // rescale (acc) ordered after pv by data deps

        __syncthreads();  // stage drained + all buffer reads complete
    }

    // ---- tail: PV(NT-1)
    {
        char* vP = ((NT - 1) & 1) ? V1 : V0;
        pv(vP);
    }

    if (SPLIT) {
        float* pa_ = pacc + (size_t)half * 16384 * 256;
#pragma unroll
        for (int r = 0; r < 4; ++r) {
            int row = qw + lg * 4 + r;
#pragma unroll
            for (int dt = 0; dt < 16; ++dt)
                pa_[(size_t)row * 256 + dt * 16 + lr] = acc[dt][r];
            if (lr == 0) pl[half * 16384 + row] = lacc[r];
        }
        if (l < 16) pm[half * 16384 + qw + lr] = mrow;
    } else {
#pragma unroll
        for (int r = 0; r < 4; ++r) {
            float inv = 1.0f / lacc[r];
#pragma unroll
            for (int dt = 0; dt < 16; ++dt)
                out[(size_t)(qw + lg * 4 + r) * 256 + dt * 16 + lr]
                    = acc[dt][r] * inv;
        }
    }
}

// ---------------------------------------------------------------------------
// Combine the two kv-split partials.
// ---------------------------------------------------------------------------
__global__ __launch_bounds__(256)
void combine_kernel(const float* __restrict__ pacc, const float* __restrict__ pm,
                    const float* __restrict__ pl, float* __restrict__ out)
{
    int idx = blockIdx.x * 256 + threadIdx.x;
    int row = idx >> 6, c4 = (idx & 63) * 4;
    float m0 = pm[row], m1 = pm[16384 + row];
    float l0 = pl[row], l1 = pl[16384 + row];
    float m  = fmaxf(m0, m1);
    float a  = __expf(m0 - m), b = __expf(m1 - m);
    float inv = 1.0f / (l0 * a + l1 * b);
    float4 x0 = *(const float4*)(pacc + (size_t)row * 256 + c4);
    float4 x1 = *(const float4*)(pacc + (size_t)16384 * 256 + (size_t)row * 256 + c4);
    float4 o;
    o.x = (x0.x * a + x1.x * b) * inv;
    o.y = (x0.y * a + x1.y * b) * inv;
    o.z = (x0.z * a + x1.z * b) * inv;
    o.w = (x0.w * a + x1.w * b) * inv;
    *(float4*)(out + (size_t)row * 256 + c4) = o;
}

// ---------------------------------------------------------------------------
extern "C" void kernel_launch(void* const* d_in, const int* in_sizes, int n_in,
                              void* d_out, int out_size, void* d_ws, size_t ws_size,
                              hipStream_t stream)
{
    const float* gE   = (const float*)d_in[0];
    const float* sE   = (const float*)d_in[1];
    const float* wgt  = (const float*)d_in[2];
    const int*   mask = (const int*)  d_in[3];
    const float* Wq   = (const float*)d_in[4];
    const float* bq   = (const float*)d_in[5];
    const float* Wk   = (const float*)d_in[6];
    const float* bk   = (const float*)d_in[7];
    float* out = (float*)d_out;

    char* ws = (char*)d_ws;
    bf16_t* Qb = (bf16_t*)ws;                              //  8 MB @ 0
    bf16_t* Kb = (bf16_t*)(ws + 8388608);                  //  2 MB (pre-swz)
    bf16_t* VT = (bf16_t*)(ws + 10485760);                 //  2 MB (pre-swz)
    float*  pacc = (float*)(ws + 12582912);                // 32 MB (2 splits)
    float*  pm   = (float*)(ws + 46137344);                // 128 KB
    float*  pl   = (float*)(ws + 46268416);                // 128 KB
    const size_t need_full = 46399488;
    const size_t need_min  = 12582912;

    if (ws_size < need_min) return;

    proj_kernel<512, false><<<dim3(256, 1), 256, 0, stream>>>(gE, Wq, bq, Qb, 0.0625f);
    proj_kernel<256, true ><<<dim3(64, 1), 256, 0, stream>>>(sE, Wk, bk, Kb, 1.0f);
    buildvt_kernel<<<4096, 256, 0, stream>>>(sE, wgt, VT);

    if (ws_size >= need_full) {
        attn_kernel<true><<<dim3(128, 2), 512, 0, stream>>>(
            Qb, Kb, VT, mask, out, pacc, pm, pl);
        combine_kernel<<<4096, 256, 0, stream>>>(pacc, pm, pl, out);
    } else {
        attn_kernel<false><<<dim3(128, 1), 512, 0, stream>>>(
            Qb, Kb, VT, mask, out, nullptr, nullptr, nullptr);
    }
}

// Round 19
// 178.740 us; speedup vs baseline: 1.0903x; 1.0903x over previous
//
#include <hip/hip_runtime.h>
#include <hip/hip_bf16.h>

typedef __bf16 bf16_t;
typedef bf16_t bf16x8 __attribute__((ext_vector_type(8)));
typedef float  f32x4  __attribute__((ext_vector_type(4)));
typedef unsigned long long u64;
typedef unsigned int u32;

#define MFMA16(A,B,C) __builtin_amdgcn_mfma_f32_16x16x32_bf16((A),(B),(C),0,0,0)

// NQ=16384, NK=4096, QDIM=512, KDIM=256, MID=256

// async global -> LDS, 16B per lane; LDS dest = wave-uniform base + lane*16.
static __device__ __forceinline__ void gl_lds16(const bf16_t* g, void* l) {
    __builtin_amdgcn_global_load_lds(
        (const __attribute__((address_space(1))) u32*)(const void*)g,
        (__attribute__((address_space(3))) u32*)l, 16, 0, 0);
}

// ---------------------------------------------------------------------------
// C_bf16[M][256] = (A_f32[M][KA] @ W_f32[256][KA]^T + b[256]) * scale
// SWZ: 16B chunk c of row stored at c ^ (row&7)  (verified r9/r12/r13)
// ---------------------------------------------------------------------------
template<int KA, bool SWZ>
__global__ __launch_bounds__(256)
void proj_kernel(const float* __restrict__ A, const float* __restrict__ W,
                 const float* __restrict__ b, bf16_t* __restrict__ C,
                 float scale)
{
    __shared__ bf16_t Alds[64][40];
    __shared__ bf16_t Wlds[256][40];

    const int t  = threadIdx.x;
    const int w  = t >> 6, l = t & 63, lr = l & 15, lg = l >> 4;
    const int m0 = blockIdx.x * 64;

    f32x4 acc[16];
#pragma unroll
    for (int tt = 0; tt < 16; ++tt) acc[tt] = (f32x4){0.f, 0.f, 0.f, 0.f};

    const int ar  = t >> 2;
    const int ac8 = (t & 3) * 8;

    for (int kb = 0; kb < KA / 32; ++kb) {
        {
            const float* ap = A + (size_t)(m0 + ar) * KA + kb * 32 + ac8;
            float4 a0 = *(const float4*)ap;
            float4 a1 = *(const float4*)(ap + 4);
            bf16x8 av;
            av[0]=(bf16_t)a0.x; av[1]=(bf16_t)a0.y; av[2]=(bf16_t)a0.z; av[3]=(bf16_t)a0.w;
            av[4]=(bf16_t)a1.x; av[5]=(bf16_t)a1.y; av[6]=(bf16_t)a1.z; av[7]=(bf16_t)a1.w;
            *(bf16x8*)&Alds[ar][ac8] = av;
        }
#pragma unroll
        for (int c = 0; c < 4; ++c) {
            int e8 = c * 256 + t;
            int wr = e8 >> 2, wc8 = (e8 & 3) * 8;
            const float* wp = W + (size_t)wr * KA + kb * 32 + wc8;
            float4 w0 = *(const float4*)wp;
            float4 w1 = *(const float4*)(wp + 4);
            bf16x8 wv;
            wv[0]=(bf16_t)w0.x; wv[1]=(bf16_t)w0.y; wv[2]=(bf16_t)w0.z; wv[3]=(bf16_t)w0.w;
            wv[4]=(bf16_t)w1.x; wv[5]=(bf16_t)w1.y; wv[6]=(bf16_t)w1.z; wv[7]=(bf16_t)w1.w;
            *(bf16x8*)&Wlds[wr][wc8] = wv;
        }
        __syncthreads();

        bf16x8 af = *(bf16x8*)&Alds[w * 16 + lr][lg * 8];
#pragma unroll
        for (int tt = 0; tt < 16; ++tt) {
            bf16x8 bfrag = *(bf16x8*)&Wlds[tt * 16 + lr][lg * 8];
            acc[tt] = MFMA16(af, bfrag, acc[tt]);
        }
        __syncthreads();
    }

#pragma unroll
    for (int tt = 0; tt < 16; ++tt) {
        int col = tt * 16 + lr;
        float bias = b[col];
#pragma unroll
        for (int r = 0; r < 4; ++r) {
            int row = m0 + w * 16 + lg * 4 + r;
            int colS = col;
            if (SWZ) colS = (((col >> 3) ^ (row & 7)) << 3) | (col & 7);
            C[(size_t)row * 256 + colS] = (bf16_t)((acc[tt][r] + bias) * scale);
        }
    }
}

// ---------------------------------------------------------------------------
// VTg chunk-major (verified r15): per 32-kv tile kb, [4 chunks c][256 d][8 j];
// VTg[((kb*4 + c)*256 + d)*8 + j] = w[k]*S[k][d],  k = kb*32 + c*8 + j.
// LDS tile = linear 16KB copy; PV reads land 2 lanes/bank (conflict-free).
// ---------------------------------------------------------------------------
__global__ __launch_bounds__(256)
void buildvt_kernel(const float* __restrict__ S, const float* __restrict__ wgt,
                    bf16_t* __restrict__ VTg)
{
    int i = blockIdx.x * 256 + threadIdx.x;     // 0 .. 1048575
    int kb = i >> 13;                           // 32-kv tile
    int c  = (i >> 11) & 3;                     // 16B chunk
    int d  = (i >> 3) & 255;
    int j  = i & 7;
    int k  = kb * 32 + c * 8 + j;
    VTg[i] = (bf16_t)(wgt[k] * S[(size_t)k * 256 + d]);
}

// ---------------------------------------------------------------------------
// Flash attention: swapped-QK^T + merged-phase pipeline (r17) at KVBLK=32
// with 64 KB LDS -> TWO independent 256-thread blocks per CU (cross-block
// TLP fills each other's barrier/phase troughs).  4 waves x 16 q = 64 q/blk.
// K pre-swz global + XOR reads (r12); V chunk-major (r15); in-register
// softmax + cvt_pk/permlane pack (r16); ones-MFMA denominator; defer-max.
// grid (256, SPLIT?2:1); NT = 64 tiles.
// ---------------------------------------------------------------------------
template<bool SPLIT>
__global__ __launch_bounds__(256, 2)
void attn_kernel(const bf16_t* __restrict__ Qb, const bf16_t* __restrict__ Kb,
                 const bf16_t* __restrict__ VTg, const int* __restrict__ mask,
                 float* __restrict__ out, float* __restrict__ pacc,
                 float* __restrict__ pm, float* __restrict__ pl)
{
    __shared__ __align__(16) char Kraw[2][16384];  // K [32][512B] (pre-swz)
    __shared__ __align__(16) char Vraw[2][16384];  // V [4][256][16B] chunk-major

    const int t  = threadIdx.x;
    const int w  = t >> 6, l = t & 63, lr = l & 15, lg = l >> 4;
    const int qw = blockIdx.x * 64 + w * 16;       // wave's 16 q-rows
    const int half = SPLIT ? (int)blockIdx.y : 0;
    const int NT   = SPLIT ? 64 : 128;             // 32-kv tiles
    const int kb0  = half * NT;

    // hoist Q fragments (lane: q-row = qw+lr, k = kk*32 + lg*8 + j)
    bf16x8 qf[8];
    {
        const bf16_t* qrow = Qb + (size_t)(qw + lr) * 256;
#pragma unroll
        for (int kk = 0; kk < 8; ++kk)
            qf[kk] = *(const bf16x8*)(qrow + kk * 32 + lg * 8);
    }

    bf16x8 vone;
#pragma unroll
    for (int j = 0; j < 8; ++j) vone[j] = (bf16_t)1.0f;

    f32x4 acc[16];                 // C-layout: q = lg*4+r, d = dt*16+lr
#pragma unroll
    for (int dt = 0; dt < 16; ++dt) acc[dt] = (f32x4){0.f, 0.f, 0.f, 0.f};
    f32x4 lacc = (f32x4){0.f, 0.f, 0.f, 0.f};   // row-sum (P @ 1), C-layout
    float mrow = -1e30f;           // running max, per-lane (q = qw+lr)
    bf16x8 pa;                     // current tile's P A-frag (kv 0..31)

    char* const K0 = &Kraw[0][0];
    char* const K1 = &Kraw[1][0];
    char* const V0 = &Vraw[0][0];
    char* const V1 = &Vraw[1][0];

    auto stageK = [&](int kb, char* kd) {
#pragma unroll
        for (int i = 0; i < 4; ++i) {          // K: wave w -> rows w*8..+7
            int row = w * 8 + i * 2 + (l >> 5);
            gl_lds16(Kb + (size_t)(kb * 32 + row) * 256 + (l & 31) * 8,
                     kd + (w * 8 + i * 2) * 512);
        }
    };
    auto stageV = [&](int kb, char* vd) {
#pragma unroll
        for (int i = 0; i < 4; ++i) {          // V: wave w -> 4KB contiguous
            gl_lds16(VTg + (size_t)kb * 8192 + w * 2048 + i * 512 + l * 8,
                     vd + w * 4096 + i * 1024);
        }
    };

    // S^T = K Q^T: lane (lr,lg) reg (tt,r) = S[kv=16tt+4lg+r][q=qw+lr]
    auto qk = [&](char* kcur, f32x4 (&s)[2]) {
#pragma unroll
        for (int tt = 0; tt < 2; ++tt) {
            f32x4 sv = (f32x4){0.f, 0.f, 0.f, 0.f};
#pragma unroll
            for (int kk = 0; kk < 8; ++kk) {
                bf16x8 kf = *(bf16x8*)(kcur + (((tt * 16 + lr) * 512)
                                | ((((kk * 4 + lg) ^ (lr & 7)) << 4))));
                sv = MFMA16(kf, qf[kk], sv);
            }
            s[tt] = sv;
        }
    };

    // PV(t): acc/lacc += pa . V  (C-layout); chunk-major V reads (r15)
    auto pv = [&](char* vcur) {
        lacc = MFMA16(pa, vone, lacc);
#pragma unroll
        for (int dt = 0; dt < 16; ++dt) {
            bf16x8 vf = *(bf16x8*)(vcur + lg * 4096 + (dt * 16 + lr) * 16);
            acc[dt] = MFMA16(pa, vf, acc[dt]);
        }
    };

    // mask, row-max, defer-rescale, exp, pack -> pa   (r16-verified pieces)
    auto softmax = [&](int4 (&mv)[2], f32x4 (&s)[2]) {
#pragma unroll
        for (int tt = 0; tt < 2; ++tt) {
            s[tt][0] = mv[tt].x ? s[tt][0] : -1e30f;
            s[tt][1] = mv[tt].y ? s[tt][1] : -1e30f;
            s[tt][2] = mv[tt].z ? s[tt][2] : -1e30f;
            s[tt][3] = mv[tt].w ? s[tt][3] : -1e30f;
        }
        float bm;
        {
            f32x4 m4;
            m4[0] = fmaxf(s[0][0], s[1][0]);
            m4[1] = fmaxf(s[0][1], s[1][1]);
            m4[2] = fmaxf(s[0][2], s[1][2]);
            m4[3] = fmaxf(s[0][3], s[1][3]);
            bm = fmaxf(fmaxf(m4[0], m4[1]), fmaxf(m4[2], m4[3]));
            bm = fmaxf(bm, __shfl_xor(bm, 16));
            bm = fmaxf(bm, __shfl_xor(bm, 32));
        }
        bool need = bm > mrow + 8.f;
        if (__any(need)) {
            float mn = fmaxf(mrow, bm);
            float fr = __expf(mrow - mn);
            mrow = mn;
            float frC[4];
#pragma unroll
            for (int r = 0; r < 4; ++r) frC[r] = __shfl(fr, lg * 4 + r);
#pragma unroll
            for (int r = 0; r < 4; ++r) {
                lacc[r] *= frC[r];
#pragma unroll
                for (int dt = 0; dt < 16; ++dt) acc[dt][r] *= frC[r];
            }
        }
#pragma unroll
        for (int tt = 0; tt < 2; ++tt)
#pragma unroll
            for (int r = 0; r < 4; ++r)
                s[tt][r] = __expf(s[tt][r] - mrow);

        // pack: pa element j = P[q=qw+lr][kv = 8lg + j]
        {
            u32 x0, x1, y0, y1;
            asm("v_cvt_pk_bf16_f32 %0, %1, %2"
                : "=v"(x0) : "v"(s[0][0]), "v"(s[0][1]));
            asm("v_cvt_pk_bf16_f32 %0, %1, %2"
                : "=v"(x1) : "v"(s[0][2]), "v"(s[0][3]));
            asm("v_cvt_pk_bf16_f32 %0, %1, %2"
                : "=v"(y0) : "v"(s[1][0]), "v"(s[1][1]));
            asm("v_cvt_pk_bf16_f32 %0, %1, %2"
                : "=v"(y1) : "v"(s[1][2]), "v"(s[1][3]));
            asm volatile("v_permlane32_swap_b32 %0, %1" : "+v"(x0), "+v"(y0));
            asm volatile("v_permlane32_swap_b32 %0, %1" : "+v"(x1), "+v"(y1));
            u32 sx0 = (u32)__shfl_xor((int)x0, 16);
            u32 sx1 = (u32)__shfl_xor((int)x1, 16);
            u32 sy0 = (u32)__shfl_xor((int)y0, 16);
            u32 sy1 = (u32)__shfl_xor((int)y1, 16);
            bool evn = (lg & 1) == 0;
            union { u32 uw[4]; bf16x8 v; } pu;
            pu.uw[0] = evn ? x0  : sy0;
            pu.uw[1] = evn ? x1  : sy1;
            pu.uw[2] = evn ? sx0 : y0;
            pu.uw[3] = evn ? sx1 : y1;
            pa = pu.v;
        }
    };

    // ---- prologue: tile 0 staged, QK(0)+softmax(0) -> pa; K(1) staged
    stageV(kb0, V0);
    stageK(kb0, K0);
    __syncthreads();
    {
        int4 mv[2];
#pragma unroll
        for (int tt = 0; tt < 2; ++tt)
            mv[tt] = *(const int4*)(mask + (size_t)(qw + lr) * 4096
                                    + kb0 * 32 + tt * 16 + lg * 4);
        f32x4 s[2];
        qk(K0, s);
        softmax(mv, s);
    }
    stageK(kb0 + 1, K1);
    __syncthreads();

    // ---- main pipeline: iter tb computes QK(tb+1) || PV(tb)
    for (int tb = 0; tb < NT - 1; ++tb) {
        char* kQ = (tb & 1) ? K0 : K1;   // QK(tb+1) source
        char* vP = (tb & 1) ? V1 : V0;   // PV(tb) source
        char* kS = (tb & 1) ? K1 : K0;   // stage K(tb+2) dest
        char* vS = (tb & 1) ? V0 : V1;   // stage V(tb+1) dest
        const int kb = kb0 + tb;

        int4 mv[2];
#pragma unroll
        for (int tt = 0; tt < 2; ++tt)
            mv[tt] = *(const int4*)(mask + (size_t)(qw + lr) * 4096
                                    + (kb + 1) * 32 + tt * 16 + lg * 4);

        stageV(kb + 1, vS);
        if (tb + 2 < NT) stageK(kb + 2, kS);

        __builtin_amdgcn_s_setprio(1);
        f32x4 s[2];
        qk(kQ, s);        // independent of pv below -> compiler interleaves
        pv(vP);
        __builtin_amdgcn_s_setprio(0);

        softmax(mv, s);   // rescale (acc) ordered after pv by data deps

        __syncthreads();  // stage drained + all buffer reads complete
    }

    // ---- tail: PV(NT-1)
    {
        char* vP = ((NT - 1) & 1) ? V1 : V0;
        pv(vP);
    }

    if (SPLIT) {
        float* pa_ = pacc + (size_t)half * 16384 * 256;
#pragma unroll
        for (int r = 0; r < 4; ++r) {
            int row = qw + lg * 4 + r;
#pragma unroll
            for (int dt = 0; dt < 16; ++dt)
                pa_[(size_t)row * 256 + dt * 16 + lr] = acc[dt][r];
            if (lr == 0) pl[half * 16384 + row] = lacc[r];
        }
        if (l < 16) pm[half * 16384 + qw + lr] = mrow;
    } else {
#pragma unroll
        for (int r = 0; r < 4; ++r) {
            float inv = 1.0f / lacc[r];
#pragma unroll
            for (int dt = 0; dt < 16; ++dt)
                out[(size_t)(qw + lg * 4 + r) * 256 + dt * 16 + lr]
                    = acc[dt][r] * inv;
        }
    }
}

// ---------------------------------------------------------------------------
// Combine the two kv-split partials.
// ---------------------------------------------------------------------------
__global__ __launch_bounds__(256)
void combine_kernel(const float* __restrict__ pacc, const float* __restrict__ pm,
                    const float* __restrict__ pl, float* __restrict__ out)
{
    int idx = blockIdx.x * 256 + threadIdx.x;
    int row = idx >> 6, c4 = (idx & 63) * 4;
    float m0 = pm[row], m1 = pm[16384 + row];
    float l0 = pl[row], l1 = pl[16384 + row];
    float m  = fmaxf(m0, m1);
    float a  = __expf(m0 - m), b = __expf(m1 - m);
    float inv = 1.0f / (l0 * a + l1 * b);
    float4 x0 = *(const float4*)(pacc + (size_t)row * 256 + c4);
    float4 x1 = *(const float4*)(pacc + (size_t)16384 * 256 + (size_t)row * 256 + c4);
    float4 o;
    o.x = (x0.x * a + x1.x * b) * inv;
    o.y = (x0.y * a + x1.y * b) * inv;
    o.z = (x0.z * a + x1.z * b) * inv;
    o.w = (x0.w * a + x1.w * b) * inv;
    *(float4*)(out + (size_t)row * 256 + c4) = o;
}

// ---------------------------------------------------------------------------
extern "C" void kernel_launch(void* const* d_in, const int* in_sizes, int n_in,
                              void* d_out, int out_size, void* d_ws, size_t ws_size,
                              hipStream_t stream)
{
    const float* gE   = (const float*)d_in[0];
    const float* sE   = (const float*)d_in[1];
    const float* wgt  = (const float*)d_in[2];
    const int*   mask = (const int*)  d_in[3];
    const float* Wq   = (const float*)d_in[4];
    const float* bq   = (const float*)d_in[5];
    const float* Wk   = (const float*)d_in[6];
    const float* bk   = (const float*)d_in[7];
    float* out = (float*)d_out;

    char* ws = (char*)d_ws;
    bf16_t* Qb = (bf16_t*)ws;                              //  8 MB @ 0
    bf16_t* Kb = (bf16_t*)(ws + 8388608);                  //  2 MB (pre-swz)
    bf16_t* VT = (bf16_t*)(ws + 10485760);                 //  2 MB (chunk-major)
    float*  pacc = (float*)(ws + 12582912);                // 32 MB (2 splits)
    float*  pm   = (float*)(ws + 46137344);                // 128 KB
    float*  pl   = (float*)(ws + 46268416);                // 128 KB
    const size_t need_full = 46399488;
    const size_t need_min  = 12582912;

    if (ws_size < need_min) return;

    proj_kernel<512, false><<<dim3(256, 1), 256, 0, stream>>>(gE, Wq, bq, Qb, 0.0625f);
    proj_kernel<256, true ><<<dim3(64, 1), 256, 0, stream>>>(sE, Wk, bk, Kb, 1.0f);
    buildvt_kernel<<<4096, 256, 0, stream>>>(sE, wgt, VT);

    if (ws_size >= need_full) {
        attn_kernel<true><<<dim3(256, 2), 256, 0, stream>>>(
            Qb, Kb, VT, mask, out, pacc, pm, pl);
        combine_kernel<<<4096, 256, 0, stream>>>(pacc, pm, pl, out);
    } else {
        attn_kernel<false><<<dim3(256, 1), 256, 0, stream>>>(
            Qb, Kb, VT, mask, out, nullptr, nullptr, nullptr);
    }
}